// Round 1
// baseline (67.958 us; speedup 1.0000x reference)
//
#include <hip/hip_runtime.h>

// EmbeddingBag(mode='mean'): B=1024, S=256, W=16, EMB=50, vocab=256.
// out[bag, e] = sum_{w < len[bag]} table[chars[bag,w], e] / len[bag]
//
// Layout: one thread per float2 of output (25 threads per bag).
// - Output stores: consecutive tid -> consecutive float2 -> fully coalesced.
// - All 16 chars loaded as 4x int4 up front (padded entries are valid
//   indices in [0,256), just masked out of the sum) -> 16 independent
//   table gathers, no load-load dependency chain.
// - Table (51.2 KB) lives in L1/L2; gathers within a bag's 25 lanes read
//   consecutive float2 of one row -> coalesce into few cache transactions.

constexpr int W      = 16;
constexpr int EMB    = 50;
constexpr int J      = EMB / 2;          // 25 float2 per bag
constexpr int NBAGS  = 1024 * 256;       // 262144
constexpr int TOTAL  = NBAGS * J;        // 6,553,600 threads (divisible by 256)

__global__ __launch_bounds__(256) void embag_mean_kernel(
    const int*   __restrict__ chars,     // [NBAGS, W]
    const int*   __restrict__ lengths,   // [NBAGS]
    const float* __restrict__ table,     // [256, EMB]
    float*       __restrict__ out)       // [NBAGS, EMB]
{
    const int tid = blockIdx.x * 256 + threadIdx.x;
    const unsigned bag = (unsigned)tid / (unsigned)J;   // magic-mul div by 25
    const unsigned j   = (unsigned)tid - bag * (unsigned)J;

    const int len = lengths[bag];

    // Load the whole bag of 16 char indices (64 B, 16B-aligned).
    const int4* cp = reinterpret_cast<const int4*>(chars + bag * W);
    const int4 c0 = cp[0], c1 = cp[1], c2 = cp[2], c3 = cp[3];
    const int cs[W] = {c0.x, c0.y, c0.z, c0.w,
                       c1.x, c1.y, c1.z, c1.w,
                       c2.x, c2.y, c2.z, c2.w,
                       c3.x, c3.y, c3.z, c3.w};

    const float2* t2 = reinterpret_cast<const float2*>(table);

    float ax = 0.f, ay = 0.f;
    #pragma unroll
    for (int w = 0; w < W; ++w) {
        // Unconditional gather (index always valid); predicated accumulate.
        const float2 t = t2[cs[w] * J + j];
        const bool m = (w < len);
        ax += m ? t.x : 0.f;
        ay += m ? t.y : 0.f;
    }

    const float inv = 1.0f / (float)len;
    reinterpret_cast<float2*>(out)[tid] = make_float2(ax * inv, ay * inv);
}

extern "C" void kernel_launch(void* const* d_in, const int* in_sizes, int n_in,
                              void* d_out, int out_size, void* d_ws, size_t ws_size,
                              hipStream_t stream) {
    const int*   chars   = (const int*)d_in[0];   // [B,S,W] int32
    const int*   lengths = (const int*)d_in[1];   // [B,S]   int32
    const float* table   = (const float*)d_in[2]; // [256,50] f32
    float*       out     = (float*)d_out;         // [B,S,50] f32

    const int blocks = TOTAL / 256;  // 25600, exact
    embag_mean_kernel<<<dim3(blocks), dim3(256), 0, stream>>>(chars, lengths, table, out);
}

// Round 2
// 35.844 us; speedup vs baseline: 1.8959x; 1.8959x over previous
//
#include <hip/hip_runtime.h>

// EmbeddingBag(mode='mean'): B=1024, S=256, W=16, EMB=50, vocab=256.
// Round 2: table staged in LDS (51.4 KB incl. a zero sentinel row + 1/len LUT).
// - Grid-stride over "chunks" of 20 bags x 25 lanes (500/512 lanes active),
//   768 resident blocks -> staging traffic 768*51KB = 39 MB L2 (negligible).
// - Gather = ds_read_b64 with 32-bit addr (1 v_mad_u32_u24 each).
// - Padded slots: index -> sentinel row 256 (zeros) via 1 cndmask, then
//   unconditional accumulate.
// - 1/len exact via LDS LUT (no v_div sequence).

constexpr int W      = 16;
constexpr int EMB    = 50;            // floats per row
constexpr int ROWS   = 257;           // 256 vocab + 1 zero sentinel row
constexpr int TBL_F  = ROWS * EMB;    // 12850 floats
constexpr int LUT0   = TBL_F;         // inv-len LUT base (17 entries)
constexpr int LDS_F  = TBL_F + 17;
constexpr int NBAGS  = 1024 * 256;    // 262144
constexpr int BAGS_PER_CHUNK = 20;    // 20 bags * 25 lanes = 500 of 512 threads
constexpr int NCHUNK = (NBAGS + BAGS_PER_CHUNK - 1) / BAGS_PER_CHUNK; // 13108
constexpr int BLOCKS = 768;           // ~3 per CU

__global__ __launch_bounds__(512) void embag_mean_lds_kernel(
    const int*   __restrict__ chars,     // [NBAGS, W]
    const int*   __restrict__ lengths,   // [NBAGS]
    const float* __restrict__ table,     // [256, EMB]
    float*       __restrict__ out)       // [NBAGS, EMB]
{
    __shared__ float lds[LDS_F];

    // Stage table + zero row + inv-len LUT.
    for (int i = threadIdx.x; i < TBL_F; i += 512)
        lds[i] = (i < 256 * EMB) ? table[i] : 0.0f;
    if (threadIdx.x < 17)
        lds[LUT0 + threadIdx.x] =
            (threadIdx.x == 0) ? 0.0f : 1.0f / (float)threadIdx.x;
    __syncthreads();

    const int lb = threadIdx.x / 25;       // bag-in-chunk, 0..20
    const int j  = threadIdx.x % 25;       // float2 index within row
    const bool active = (lb < BAGS_PER_CHUNK);
    const int j2 = j * 2;                  // dword offset within row

    for (int chunk = blockIdx.x; chunk < NCHUNK; chunk += BLOCKS) {
        const int bag = chunk * BAGS_PER_CHUNK + lb;
        if (!active || bag >= NBAGS) continue;

        const int len = lengths[bag];

        const int4* cp = reinterpret_cast<const int4*>(chars + (size_t)bag * W);
        const int4 c0 = cp[0], c1 = cp[1], c2 = cp[2], c3 = cp[3];
        const int cs[W] = {c0.x, c0.y, c0.z, c0.w,
                           c1.x, c1.y, c1.z, c1.w,
                           c2.x, c2.y, c2.z, c2.w,
                           c3.x, c3.y, c3.z, c3.w};

        float ax = 0.f, ay = 0.f;
        #pragma unroll
        for (int w = 0; w < W; ++w) {
            const int ce = (w < len) ? cs[w] : 256;      // sentinel -> zero row
            const float2 v =
                *reinterpret_cast<const float2*>(&lds[ce * EMB + j2]);
            ax += v.x;
            ay += v.y;
        }

        const float inv = lds[LUT0 + len];
        const unsigned oidx = (unsigned)bag * (EMB / 2) + (unsigned)j;
        reinterpret_cast<float2*>(out)[oidx] = make_float2(ax * inv, ay * inv);
    }
}

extern "C" void kernel_launch(void* const* d_in, const int* in_sizes, int n_in,
                              void* d_out, int out_size, void* d_ws, size_t ws_size,
                              hipStream_t stream) {
    const int*   chars   = (const int*)d_in[0];   // [B,S,W] int32
    const int*   lengths = (const int*)d_in[1];   // [B,S]   int32
    const float* table   = (const float*)d_in[2]; // [256,50] f32
    float*       out     = (float*)d_out;         // [B,S,50] f32

    embag_mean_lds_kernel<<<dim3(BLOCKS), dim3(512), 0, stream>>>(
        chars, lengths, table, out);
}

// Round 3
// 26.922 us; speedup vs baseline: 2.5242x; 1.3314x over previous
//
#include <hip/hip_runtime.h>

// EmbeddingBag(mode='mean'): B=1024, S=256, W=16, EMB=50, vocab=256.
// Round 3:
//  - 1024-thread blocks, 57.7 KB LDS -> 2 blocks/CU (115 KB < 160 KB),
//    __launch_bounds__(1024, 8) caps VGPR<=64 -> 32 waves/CU (~100% occ).
//  - Table rows padded to 56 dwords (224 B, 16B-aligned) -> ds_read_b128
//    gathers, 13 threads per bag (12 x float4 + 1 x float2 tail).
//  - Early exit on groups of 4 chars: avg rows gathered 16 -> ~10.
//  - Sentinel zero row (index 256) masks the partial group, 1/len LUT.

constexpr int W       = 16;
constexpr int EMB     = 50;
constexpr int RSTRIDE = 56;                 // padded row stride in dwords
constexpr int ROWS    = 257;                // 256 vocab + zero sentinel
constexpr int TBL_F   = ROWS * RSTRIDE;     // 14392 floats
constexpr int LUT0    = TBL_F;              // 1/len LUT base
constexpr int LDS_F   = TBL_F + 17;         // 57,636 B
constexpr int NBAGS   = 1024 * 256;         // 262144
constexpr int TPB     = 13;                 // threads per bag
constexpr int BLOCK   = 1024;
constexpr int BAGS_PER_CHUNK = BLOCK / TPB; // 78 (1014 active lanes)
constexpr int NCHUNK  = (NBAGS + BAGS_PER_CHUNK - 1) / BAGS_PER_CHUNK; // 3361
constexpr int BLOCKS  = 512;                // 2 resident per CU

__global__ __launch_bounds__(BLOCK, 8) void embag_b128_kernel(
    const int*   __restrict__ chars,     // [NBAGS, W]
    const int*   __restrict__ lengths,   // [NBAGS]
    const float* __restrict__ table,     // [256, EMB]
    float*       __restrict__ out)       // [NBAGS, EMB]
{
    __shared__ float lds[LDS_F];

    // Stage table into padded layout; row 256 and cols 50..55 are zeros.
    for (int i = threadIdx.x; i < TBL_F; i += BLOCK) {
        const int r = i / RSTRIDE;
        const int c = i - r * RSTRIDE;
        lds[i] = (r < 256 && c < EMB) ? table[r * EMB + c] : 0.0f;
    }
    if (threadIdx.x < 17)
        lds[LUT0 + threadIdx.x] =
            (threadIdx.x == 0) ? 0.0f : 1.0f / (float)threadIdx.x;
    __syncthreads();

    const int  lb     = threadIdx.x / TPB;            // bag within chunk
    const int  t      = threadIdx.x - lb * TPB;       // float4 slot 0..12
    const bool active = (lb < BAGS_PER_CHUNK);
    const float* rowp = lds + 4 * t;                  // 16B-aligned per row

    for (int chunk = blockIdx.x; chunk < NCHUNK; chunk += BLOCKS) {
        const int bag = chunk * BAGS_PER_CHUNK + lb;
        if (!active || bag >= NBAGS) continue;

        const int len = lengths[bag];

        const int4* cp = reinterpret_cast<const int4*>(chars + (size_t)bag * W);
        const int4 c0 = cp[0], c1 = cp[1], c2 = cp[2], c3 = cp[3];

        float4 acc = make_float4(0.f, 0.f, 0.f, 0.f);

        auto do4 = [&](int4 c, int wbase) {
            const int e0 = (wbase + 0 < len) ? c.x : 256;
            const int e1 = (wbase + 1 < len) ? c.y : 256;
            const int e2 = (wbase + 2 < len) ? c.z : 256;
            const int e3 = (wbase + 3 < len) ? c.w : 256;
            const float4 v0 = *reinterpret_cast<const float4*>(rowp + e0 * RSTRIDE);
            const float4 v1 = *reinterpret_cast<const float4*>(rowp + e1 * RSTRIDE);
            const float4 v2 = *reinterpret_cast<const float4*>(rowp + e2 * RSTRIDE);
            const float4 v3 = *reinterpret_cast<const float4*>(rowp + e3 * RSTRIDE);
            // keep per-element w-order identical to reference summation
            acc.x += v0.x; acc.y += v0.y; acc.z += v0.z; acc.w += v0.w;
            acc.x += v1.x; acc.y += v1.y; acc.z += v1.z; acc.w += v1.w;
            acc.x += v2.x; acc.y += v2.y; acc.z += v2.z; acc.w += v2.w;
            acc.x += v3.x; acc.y += v3.y; acc.z += v3.z; acc.w += v3.w;
        };

        do4(c0, 0);
        if (len > 4) {
            do4(c1, 4);
            if (len > 8) {
                do4(c2, 8);
                if (len > 12) {
                    do4(c3, 12);
                }
            }
        }

        const float inv = lds[LUT0 + len];
        const unsigned base = (unsigned)bag * EMB + 4u * (unsigned)t;
        float2* o = reinterpret_cast<float2*>(out + base);  // 8B-aligned (base even)
        o[0] = make_float2(acc.x * inv, acc.y * inv);
        if (t < 12)
            o[1] = make_float2(acc.z * inv, acc.w * inv);   // t==12 owns only 48,49
    }
}

extern "C" void kernel_launch(void* const* d_in, const int* in_sizes, int n_in,
                              void* d_out, int out_size, void* d_ws, size_t ws_size,
                              hipStream_t stream) {
    const int*   chars   = (const int*)d_in[0];   // [B,S,W] int32
    const int*   lengths = (const int*)d_in[1];   // [B,S]   int32
    const float* table   = (const float*)d_in[2]; // [256,50] f32
    float*       out     = (float*)d_out;         // [B,S,50] f32

    embag_b128_kernel<<<dim3(BLOCKS), dim3(BLOCK), 0, stream>>>(
        chars, lengths, table, out);
}